// Round 4
// baseline (2888.741 us; speedup 1.0000x reference)
//
#include <hip/hip_runtime.h>
#include <hip/hip_bf16.h>

// R-GCN layer (fp32 in/out): out = relu(agg0/deg0 @ W0 + agg1/deg1 @ W1 + x @ Wl + b)
// Round 4: coarse-bucket binning (128 dst-slots/bucket) + LDS fp32 bucket
// aggregation. Eliminates: per-node hist (200k-addr atomics), 200k scan, fine
// CSR fill (211 MB line-thrash writes), fp32 gathers (x converted to bf16).
//
// ws: binned uint2[2E] | xb bf16[N*128] | aggb bf16[2N*128] |
//     ghist int[NB*8] | S int[NB*8+1] | cursor int[NB*8]   (~102.6 MB)

#define DFEAT 128
#define CH 4096          // edges per bin/hist block
#define NBMAX 1600       // max buckets (M/128), N<=102400

__global__ void convert_kernel(const float4* __restrict__ x4,
                               ushort4* __restrict__ xb4, int n4) {
    int i = blockIdx.x * blockDim.x + threadIdx.x;
    if (i >= n4) return;
    float4 v = x4[i];
    ushort4 o;
    o.x = __hip_bfloat16_raw(__float2bfloat16(v.x)).x;
    o.y = __hip_bfloat16_raw(__float2bfloat16(v.y)).x;
    o.z = __hip_bfloat16_raw(__float2bfloat16(v.z)).x;
    o.w = __hip_bfloat16_raw(__float2bfloat16(v.w)).x;
    xb4[i] = o;
}

// LDS-privatized histogram over buckets b = (r*N+dst)>>7, merged per
// (b, g=blockIdx%8) so the bin pass can keep per-XCD write regions.
__global__ __launch_bounds__(256) void hist_kernel(
        const int* __restrict__ dst0, const int* __restrict__ dst1,
        int* __restrict__ ghist, int N, int E, int NB) {
    __shared__ int h[NBMAX];
    int tid = threadIdx.x;
    for (int i = tid; i < NBMAX; i += 256) h[i] = 0;
    __syncthreads();
    int k = blockIdx.x, g = k & 7;
    int lo = k * CH, hi = min(2 * E, lo + CH);
    for (int i = lo + tid; i < hi; i += 256) {
        int r = (i >= E) ? 1 : 0;
        int e = i - r * E;
        int t = r ? dst1[e] : dst0[e];
        atomicAdd(&h[(r * N + t) >> 7], 1);
    }
    __syncthreads();
    for (int b = tid; b < NB; b += 256) {
        int c = h[b];
        if (c) atomicAdd(&ghist[b * 8 + g], c);
    }
}

// Exclusive scan of ghist[n] -> S (and cursor copy); S[n] = total sentinel.
__global__ __launch_bounds__(256) void scan_kernel(const int* __restrict__ ghist,
                                                   int* __restrict__ S,
                                                   int* __restrict__ cursor,
                                                   int n, int total) {
    __shared__ int psum[256];
    int t = threadIdx.x;
    int cs = (n + 255) / 256;
    int s = 0;
    for (int j = 0; j < cs; ++j) {
        int idx = t * cs + j;
        if (idx < n) s += ghist[idx];
    }
    psum[t] = s; __syncthreads();
    for (int off = 1; off < 256; off <<= 1) {
        int add = (t >= off) ? psum[t - off] : 0;
        __syncthreads();
        psum[t] += add;
        __syncthreads();
    }
    int run = psum[t] - s;   // exclusive base
    for (int j = 0; j < cs; ++j) {
        int idx = t * cs + j;
        if (idx < n) { S[idx] = run; cursor[idx] = run; run += ghist[idx]; }
    }
    if (t == 0) S[n] = total;
}

// Scatter (src, p) into bucket regions. Per-(b,g) cursors: adjacent-in-time
// winners get adjacent slots; g partition keeps a region's writers on (mostly)
// one XCD -> line-friendly writes.
__global__ __launch_bounds__(256) void bin_kernel(
        const int* __restrict__ src0, const int* __restrict__ dst0,
        const int* __restrict__ src1, const int* __restrict__ dst1,
        int* __restrict__ cursor, uint2* __restrict__ binned, int N, int E) {
    int k = blockIdx.x, g = k & 7;
    int lo = k * CH, hi = min(2 * E, lo + CH);
    for (int i = lo + threadIdx.x; i < hi; i += 256) {
        int r = (i >= E) ? 1 : 0;
        int e = i - r * E;
        int s = r ? src1[e] : src0[e];
        int t = r ? dst1[e] : dst0[e];
        int p = r * N + t;
        int slot = atomicAdd(&cursor[(p >> 7) * 8 + g], 1);
        binned[slot] = make_uint2((unsigned)s, (unsigned)p);
    }
}

// One block per bucket (128 p's). LDS fp32 accum [128][128]; one wave per
// edge: 64 lanes gather the 256B bf16 row of x[src], 2 ds_add_f32 per lane.
// Lane-parity swizzle keeps every bank exactly 2-way (free on CDNA4).
__global__ __launch_bounds__(256) void agg_kernel(
        const unsigned* __restrict__ xbu,      // bf16 x as uint[N][64]
        const uint2* __restrict__ binned,
        const int* __restrict__ S,
        unsigned short* __restrict__ aggb, int M) {
    __shared__ float acc[128 * 128];
    __shared__ int deg[128];
    int tid = threadIdx.x;
    float4* a4 = (float4*)acc;
    for (int i = tid; i < 4096; i += 256) a4[i] = make_float4(0.f, 0.f, 0.f, 0.f);
    if (tid < 128) deg[tid] = 0;
    __syncthreads();

    int blk = blockIdx.x;
    int estart = S[blk * 8], eend = S[blk * 8 + 8];
    int P0 = blk * 128;
    int wv = tid >> 6, lane = tid & 63;
    int sw = (lane >> 4) & 1;

    for (int idx = estart + wv; idx < eend; idx += 4) {
        uint2 ev = binned[idx];
        int src = __builtin_amdgcn_readfirstlane((int)ev.x);
        int p   = __builtin_amdgcn_readfirstlane((int)ev.y);
        unsigned xv = xbu[(long long)src * 64 + lane];
        float lo = __uint_as_float(xv << 16);            // feat 2*lane
        float hi = __uint_as_float(xv & 0xffff0000u);    // feat 2*lane+1
        float f0 = sw ? hi : lo;
        float f1 = sw ? lo : hi;
        int base = (p - P0) * 128 + 2 * lane;
        atomicAdd(&acc[base + sw], f0);
        atomicAdd(&acc[base + 1 - sw], f1);
        if (lane == 0) atomicAdd(&deg[p - P0], 1);
    }
    __syncthreads();

    int pl = tid >> 1, hf = tid & 1;
    int pg = P0 + pl;
    if (pg < M) {
        float inv = 1.0f / fmaxf((float)deg[pl], 1.0f);
        int base = pl * 128 + hf * 64;
        long long gbase = (long long)pg * 128 + hf * 64;
#pragma unroll
        for (int j = 0; j < 16; ++j) {
            float4 v = *(float4*)&acc[base + 4 * j];
            ushort4 w;
            w.x = __hip_bfloat16_raw(__float2bfloat16(v.x * inv)).x;
            w.y = __hip_bfloat16_raw(__float2bfloat16(v.y * inv)).x;
            w.z = __hip_bfloat16_raw(__float2bfloat16(v.z * inv)).x;
            w.w = __hip_bfloat16_raw(__float2bfloat16(v.w * inv)).x;
            *(ushort4*)(aggb + gbase + 4 * j) = w;
        }
    }
}

// Fused GEMM: C[node,col] over K=384 (agg bf16 [2N][128] | x fp32), bias+relu.
// (kept verbatim from round 3 — known correct; optimize with evidence next.)
__global__ __launch_bounds__(256) void fused_gemm_kernel(
        const unsigned short* __restrict__ aggb,
        const float* __restrict__ x,
        const float* __restrict__ wrel,   // [2,128,128] flat = [k<256][col]
        const float* __restrict__ wloop,  // [128,128]
        const float* __restrict__ bias,   // [128]
        float* __restrict__ out, int N) {
    __shared__ float Ash[32][33];
    __shared__ float Bsh[32][132];

    int tid = threadIdx.x;
    int nb = blockIdx.x * 32;
    int colg = tid & 31;
    int nrow = tid >> 5;

    float acc[4][4];
#pragma unroll
    for (int i = 0; i < 4; ++i)
#pragma unroll
        for (int j = 0; j < 4; ++j) acc[i][j] = 0.f;

    for (int kc = 0; kc < 12; ++kc) {
        int k0 = kc * 32;
#pragma unroll
        for (int i = 0; i < 4; ++i) {
            int lin = tid + 256 * i;
            int node = lin >> 5;
            int kk = lin & 31;
            int k = k0 + kk;
            int gnode = nb + node;
            float val = 0.f;
            if (gnode < N) {
                if (k < 256) {
                    int r = k >> 7;
                    int kloc = k & 127;
                    __hip_bfloat16_raw hr;
                    hr.x = aggb[((long long)r * N + gnode) * DFEAT + kloc];
                    val = __bfloat162float(__hip_bfloat16(hr));
                } else {
                    val = x[(long long)gnode * DFEAT + (k - 256)];
                }
            }
            Ash[kk][node] = val;
        }
#pragma unroll
        for (int i = 0; i < 16; ++i) {
            int lin = tid + 256 * i;
            int kk = lin >> 7;
            int col = lin & 127;
            int k = k0 + kk;
            float val;
            if (k < 256) val = wrel[k * DFEAT + col];
            else         val = wloop[(k - 256) * DFEAT + col];
            Bsh[kk][col] = val;
        }
        __syncthreads();

#pragma unroll
        for (int kk = 0; kk < 32; ++kk) {
            float4 b = *(const float4*)&Bsh[kk][colg * 4];
            float a0 = Ash[kk][nrow];
            float a1 = Ash[kk][nrow + 8];
            float a2 = Ash[kk][nrow + 16];
            float a3 = Ash[kk][nrow + 24];
            acc[0][0] += a0 * b.x; acc[0][1] += a0 * b.y; acc[0][2] += a0 * b.z; acc[0][3] += a0 * b.w;
            acc[1][0] += a1 * b.x; acc[1][1] += a1 * b.y; acc[1][2] += a1 * b.z; acc[1][3] += a1 * b.w;
            acc[2][0] += a2 * b.x; acc[2][1] += a2 * b.y; acc[2][2] += a2 * b.z; acc[2][3] += a2 * b.w;
            acc[3][0] += a3 * b.x; acc[3][1] += a3 * b.y; acc[3][2] += a3 * b.z; acc[3][3] += a3 * b.w;
        }
        __syncthreads();
    }

    float bv[4];
#pragma unroll
    for (int j = 0; j < 4; ++j) bv[j] = bias[colg * 4 + j];

#pragma unroll
    for (int i = 0; i < 4; ++i) {
        int gnode = nb + nrow + 8 * i;
        if (gnode < N) {
#pragma unroll
            for (int j = 0; j < 4; ++j) {
                float h = acc[i][j] + bv[j];
                out[(long long)gnode * DFEAT + colg * 4 + j] = fmaxf(h, 0.f);
            }
        }
    }
}

extern "C" void kernel_launch(void* const* d_in, const int* in_sizes, int n_in,
                              void* d_out, int out_size, void* d_ws, size_t ws_size,
                              hipStream_t stream) {
    const float* x      = (const float*)d_in[0];
    const int* src_fwd  = (const int*)d_in[1];
    const int* dst_fwd  = (const int*)d_in[2];
    const int* src_bwd  = (const int*)d_in[3];
    const int* dst_bwd  = (const int*)d_in[4];
    const float* wrel   = (const float*)d_in[5];
    const float* wloop  = (const float*)d_in[6];
    const float* hbias  = (const float*)d_in[7];
    float* out          = (float*)d_out;

    int N = in_sizes[0] / DFEAT;
    int E = in_sizes[1];
    int M = 2 * N;
    int TE = 2 * E;
    int NB = (M + 127) / 128;        // 1563
    int NB8 = NB * 8;

    uint2* binned        = (uint2*)d_ws;                           // [2E]
    unsigned short* xb   = (unsigned short*)(binned + (size_t)TE); // [N*128]
    unsigned short* aggb = xb + (size_t)N * DFEAT;                 // [2N*128]
    int* ghist           = (int*)(aggb + (size_t)M * DFEAT);       // [NB8]
    int* S               = ghist + NB8;                            // [NB8+1]
    int* cursor          = S + NB8 + 1;                            // [NB8]

    int n4 = N * (DFEAT / 4);
    convert_kernel<<<(n4 + 255) / 256, 256, 0, stream>>>(
        (const float4*)x, (ushort4*)xb, n4);

    hipMemsetAsync(ghist, 0, (size_t)NB8 * 4, stream);

    int binb = ((TE + CH - 1) / CH + 7) & ~7;   // multiple of 8
    hist_kernel<<<binb, 256, 0, stream>>>(dst_fwd, dst_bwd, ghist, N, E, NB);

    scan_kernel<<<1, 256, 0, stream>>>(ghist, S, cursor, NB8, TE);

    bin_kernel<<<binb, 256, 0, stream>>>(
        src_fwd, dst_fwd, src_bwd, dst_bwd, cursor, binned, N, E);

    agg_kernel<<<NB, 256, 0, stream>>>((const unsigned*)xb, binned, S, aggb, M);

    fused_gemm_kernel<<<(N + 31) / 32, 256, 0, stream>>>(
        aggb, x, wrel, wloop, hbias, out, N);
}

// Round 5
// 644.922 us; speedup vs baseline: 4.4792x; 4.4792x over previous
//
#include <hip/hip_runtime.h>
#include <hip/hip_bf16.h>

// R-GCN layer (fp32 in/out): out = relu(agg0/deg0 @ W0 + agg1/deg1 @ W1 + x @ Wl + b)
// Round 5: coarse-bucket binning (cheap, clustered 4B writes) + per-bucket
// local CSR in LDS (~13KB -> high occupancy) + register accumulation with
// 4-way unrolled bf16 gathers. No feature atomics; no 64KB LDS accumulator.
//
// ws: binned uint[2E] | xb bf16[N*128] | aggb bf16[2N*128] |
//     ghist int[NB*8] | S int[NB*8+1] | cursor int[NB*8]
// Requires N <= 131072 (src packed into 17 bits).

#define DFEAT 128
#define CH 4096          // edges per hist/bin block
#define NBMAX 1600       // max buckets = ceil(2N/128)
#define CAP 3328         // LDS edge capacity per bucket (mean 2048, sd ~45)

__global__ void convert_kernel(const float4* __restrict__ x4,
                               ushort4* __restrict__ xb4, int n4) {
    int i = blockIdx.x * blockDim.x + threadIdx.x;
    if (i >= n4) return;
    float4 v = x4[i];
    ushort4 o;
    o.x = __hip_bfloat16_raw(__float2bfloat16(v.x)).x;
    o.y = __hip_bfloat16_raw(__float2bfloat16(v.y)).x;
    o.z = __hip_bfloat16_raw(__float2bfloat16(v.z)).x;
    o.w = __hip_bfloat16_raw(__float2bfloat16(v.w)).x;
    xb4[i] = o;
}

// LDS-privatized histogram over buckets b=(r*N+dst)>>7, merged per (b, g=blk%8).
__global__ __launch_bounds__(256) void hist_kernel(
        const int* __restrict__ dst0, const int* __restrict__ dst1,
        int* __restrict__ ghist, int N, int E, int NB) {
    __shared__ int h[NBMAX];
    int tid = threadIdx.x;
    for (int i = tid; i < NBMAX; i += 256) h[i] = 0;
    __syncthreads();
    int k = blockIdx.x, g = k & 7;
    int lo = k * CH, hi = min(2 * E, lo + CH);
    for (int i = lo + tid; i < hi; i += 256) {
        int r = (i >= E) ? 1 : 0;
        int e = i - r * E;
        int t = r ? dst1[e] : dst0[e];
        atomicAdd(&h[(r * N + t) >> 7], 1);
    }
    __syncthreads();
    for (int b = tid; b < NB; b += 256) {
        int c = h[b];
        if (c) atomicAdd(&ghist[b * 8 + g], c);
    }
}

// Exclusive scan of ghist[n] -> S (+cursor copy); S[n] = total sentinel.
__global__ __launch_bounds__(256) void scan_kernel(const int* __restrict__ ghist,
                                                   int* __restrict__ S,
                                                   int* __restrict__ cursor,
                                                   int n, int total) {
    __shared__ int psum[256];
    int t = threadIdx.x;
    int cs = (n + 255) / 256;
    int s = 0;
    for (int j = 0; j < cs; ++j) {
        int idx = t * cs + j;
        if (idx < n) s += ghist[idx];
    }
    psum[t] = s; __syncthreads();
    for (int off = 1; off < 256; off <<= 1) {
        int add = (t >= off) ? psum[t - off] : 0;
        __syncthreads();
        psum[t] += add;
        __syncthreads();
    }
    int run = psum[t] - s;
    for (int j = 0; j < cs; ++j) {
        int idx = t * cs + j;
        if (idx < n) { S[idx] = run; cursor[idx] = run; run += ghist[idx]; }
    }
    if (t == 0) S[n] = total;
}

// Scatter packed edges (pl<<17 | src) into bucket regions, per-(b,g) cursors.
__global__ __launch_bounds__(256) void bin_kernel(
        const int* __restrict__ src0, const int* __restrict__ dst0,
        const int* __restrict__ src1, const int* __restrict__ dst1,
        int* __restrict__ cursor, unsigned* __restrict__ binned, int N, int E) {
    int k = blockIdx.x, g = k & 7;
    int lo = k * CH, hi = min(2 * E, lo + CH);
    for (int i = lo + threadIdx.x; i < hi; i += 256) {
        int r = (i >= E) ? 1 : 0;
        int e = i - r * E;
        int s = r ? src1[e] : src0[e];
        int t = r ? dst1[e] : dst0[e];
        int p = r * N + t;
        int slot = atomicAdd(&cursor[(p >> 7) * 8 + g], 1);
        binned[slot] = ((unsigned)(p & 127) << 17) | (unsigned)s;
    }
}

// One block per bucket (128 p's). Build local CSR in LDS, then one half-wave
// (32 lanes) per p: register-accumulate its in-edges via bf16 row gathers
// (uint2/lane = 256B/row), normalize by exact count, store bf16 row.
__global__ __launch_bounds__(256) void agg_kernel(
        const uint2* __restrict__ xb2,        // x bf16 rows as uint2[N][32]
        const unsigned* __restrict__ binned,
        const int* __restrict__ S,
        unsigned short* __restrict__ aggb, int M) {
    __shared__ unsigned ebuf[CAP];
    __shared__ int cnt[128], cur[128], rs[128], sh[128];
    int tid = threadIdx.x;
    int b = blockIdx.x;
    int estart = S[b * 8], eend = S[b * 8 + 8];
    int total = eend - estart;
    int P0 = b << 7;
    int hw = tid >> 5, lane = tid & 31;

    if (total <= CAP) {
        // Phase A: local CSR
        if (tid < 128) cnt[tid] = 0;
        __syncthreads();
        for (int i = estart + tid; i < eend; i += 256)
            atomicAdd(&cnt[binned[i] >> 17], 1);
        __syncthreads();
        if (tid < 128) sh[tid] = cnt[tid];
        __syncthreads();
        for (int off = 1; off < 128; off <<= 1) {
            int add = (tid < 128 && tid >= off) ? sh[tid - off] : 0;
            __syncthreads();
            if (tid < 128) sh[tid] += add;
            __syncthreads();
        }
        if (tid < 128) { rs[tid] = sh[tid] - cnt[tid]; cur[tid] = sh[tid] - cnt[tid]; }
        __syncthreads();
        for (int i = estart + tid; i < eend; i += 256) {
            unsigned v = binned[i];
            int slot = atomicAdd(&cur[v >> 17], 1);
            ebuf[slot] = v;
        }
        __syncthreads();

        // Phase B: 8 half-waves x 16 p's, register accumulation
        for (int pi = 0; pi < 16; ++pi) {
            int pl = hw * 16 + pi;
            int s0 = rs[pl], c = cnt[pl];
            float a0 = 0.f, a1 = 0.f, a2 = 0.f, a3 = 0.f;
            int e = 0;
            for (; e + 4 <= c; e += 4) {
                int sA = ebuf[s0 + e] & 0x1FFFF;
                int sB = ebuf[s0 + e + 1] & 0x1FFFF;
                int sC = ebuf[s0 + e + 2] & 0x1FFFF;
                int sD = ebuf[s0 + e + 3] & 0x1FFFF;
                uint2 gA = xb2[(long long)sA * 32 + lane];
                uint2 gB = xb2[(long long)sB * 32 + lane];
                uint2 gC = xb2[(long long)sC * 32 + lane];
                uint2 gD = xb2[(long long)sD * 32 + lane];
                a0 += __uint_as_float(gA.x << 16) + __uint_as_float(gB.x << 16)
                    + __uint_as_float(gC.x << 16) + __uint_as_float(gD.x << 16);
                a1 += __uint_as_float(gA.x & 0xffff0000u) + __uint_as_float(gB.x & 0xffff0000u)
                    + __uint_as_float(gC.x & 0xffff0000u) + __uint_as_float(gD.x & 0xffff0000u);
                a2 += __uint_as_float(gA.y << 16) + __uint_as_float(gB.y << 16)
                    + __uint_as_float(gC.y << 16) + __uint_as_float(gD.y << 16);
                a3 += __uint_as_float(gA.y & 0xffff0000u) + __uint_as_float(gB.y & 0xffff0000u)
                    + __uint_as_float(gC.y & 0xffff0000u) + __uint_as_float(gD.y & 0xffff0000u);
            }
            for (; e < c; ++e) {
                int s = ebuf[s0 + e] & 0x1FFFF;
                uint2 g = xb2[(long long)s * 32 + lane];
                a0 += __uint_as_float(g.x << 16);
                a1 += __uint_as_float(g.x & 0xffff0000u);
                a2 += __uint_as_float(g.y << 16);
                a3 += __uint_as_float(g.y & 0xffff0000u);
            }
            int pg = P0 + pl;
            if (pg < M) {
                float inv = 1.0f / (float)max(c, 1);
                ushort4 w;
                w.x = __hip_bfloat16_raw(__float2bfloat16(a0 * inv)).x;
                w.y = __hip_bfloat16_raw(__float2bfloat16(a1 * inv)).x;
                w.z = __hip_bfloat16_raw(__float2bfloat16(a2 * inv)).x;
                w.w = __hip_bfloat16_raw(__float2bfloat16(a3 * inv)).x;
                *(ushort4*)(aggb + (long long)pg * DFEAT + 4 * lane) = w;
            }
        }
    } else {
        // Fallback (statistically unreachable): scan all bucket edges per p.
        for (int pi = 0; pi < 16; ++pi) {
            int pl = hw * 16 + pi;
            float a0 = 0.f, a1 = 0.f, a2 = 0.f, a3 = 0.f;
            int c = 0;
            for (int i = estart; i < eend; ++i) {
                unsigned v = binned[i];
                if ((int)(v >> 17) == pl) {
                    ++c;
                    uint2 g = xb2[(long long)(v & 0x1FFFF) * 32 + lane];
                    a0 += __uint_as_float(g.x << 16);
                    a1 += __uint_as_float(g.x & 0xffff0000u);
                    a2 += __uint_as_float(g.y << 16);
                    a3 += __uint_as_float(g.y & 0xffff0000u);
                }
            }
            int pg = P0 + pl;
            if (pg < M) {
                float inv = 1.0f / (float)max(c, 1);
                ushort4 w;
                w.x = __hip_bfloat16_raw(__float2bfloat16(a0 * inv)).x;
                w.y = __hip_bfloat16_raw(__float2bfloat16(a1 * inv)).x;
                w.z = __hip_bfloat16_raw(__float2bfloat16(a2 * inv)).x;
                w.w = __hip_bfloat16_raw(__float2bfloat16(a3 * inv)).x;
                *(ushort4*)(aggb + (long long)pg * DFEAT + 4 * lane) = w;
            }
        }
    }
}

// Fused GEMM: C[node,col] over K=384 (agg bf16 [2N][128] | x fp32), bias+relu.
__global__ __launch_bounds__(256) void fused_gemm_kernel(
        const unsigned short* __restrict__ aggb,
        const float* __restrict__ x,
        const float* __restrict__ wrel,   // [2,128,128] flat = [k<256][col]
        const float* __restrict__ wloop,  // [128,128]
        const float* __restrict__ bias,   // [128]
        float* __restrict__ out, int N) {
    __shared__ float Ash[32][33];
    __shared__ float Bsh[32][132];

    int tid = threadIdx.x;
    int nb = blockIdx.x * 32;
    int colg = tid & 31;
    int nrow = tid >> 5;

    float acc[4][4];
#pragma unroll
    for (int i = 0; i < 4; ++i)
#pragma unroll
        for (int j = 0; j < 4; ++j) acc[i][j] = 0.f;

    for (int kc = 0; kc < 12; ++kc) {
        int k0 = kc * 32;
#pragma unroll
        for (int i = 0; i < 4; ++i) {
            int lin = tid + 256 * i;
            int node = lin >> 5;
            int kk = lin & 31;
            int k = k0 + kk;
            int gnode = nb + node;
            float val = 0.f;
            if (gnode < N) {
                if (k < 256) {
                    int r = k >> 7;
                    int kloc = k & 127;
                    __hip_bfloat16_raw hr;
                    hr.x = aggb[((long long)r * N + gnode) * DFEAT + kloc];
                    val = __bfloat162float(__hip_bfloat16(hr));
                } else {
                    val = x[(long long)gnode * DFEAT + (k - 256)];
                }
            }
            Ash[kk][node] = val;
        }
#pragma unroll
        for (int i = 0; i < 16; ++i) {
            int lin = tid + 256 * i;
            int kk = lin >> 7;
            int col = lin & 127;
            int k = k0 + kk;
            float val;
            if (k < 256) val = wrel[k * DFEAT + col];
            else         val = wloop[(k - 256) * DFEAT + col];
            Bsh[kk][col] = val;
        }
        __syncthreads();

#pragma unroll
        for (int kk = 0; kk < 32; ++kk) {
            float4 b = *(const float4*)&Bsh[kk][colg * 4];
            float a0 = Ash[kk][nrow];
            float a1 = Ash[kk][nrow + 8];
            float a2 = Ash[kk][nrow + 16];
            float a3 = Ash[kk][nrow + 24];
            acc[0][0] += a0 * b.x; acc[0][1] += a0 * b.y; acc[0][2] += a0 * b.z; acc[0][3] += a0 * b.w;
            acc[1][0] += a1 * b.x; acc[1][1] += a1 * b.y; acc[1][2] += a1 * b.z; acc[1][3] += a1 * b.w;
            acc[2][0] += a2 * b.x; acc[2][1] += a2 * b.y; acc[2][2] += a2 * b.z; acc[2][3] += a2 * b.w;
            acc[3][0] += a3 * b.x; acc[3][1] += a3 * b.y; acc[3][2] += a3 * b.z; acc[3][3] += a3 * b.w;
        }
        __syncthreads();
    }

    float bv[4];
#pragma unroll
    for (int j = 0; j < 4; ++j) bv[j] = bias[colg * 4 + j];

#pragma unroll
    for (int i = 0; i < 4; ++i) {
        int gnode = nb + nrow + 8 * i;
        if (gnode < N) {
#pragma unroll
            for (int j = 0; j < 4; ++j) {
                float h = acc[i][j] + bv[j];
                out[(long long)gnode * DFEAT + colg * 4 + j] = fmaxf(h, 0.f);
            }
        }
    }
}

extern "C" void kernel_launch(void* const* d_in, const int* in_sizes, int n_in,
                              void* d_out, int out_size, void* d_ws, size_t ws_size,
                              hipStream_t stream) {
    const float* x      = (const float*)d_in[0];
    const int* src_fwd  = (const int*)d_in[1];
    const int* dst_fwd  = (const int*)d_in[2];
    const int* src_bwd  = (const int*)d_in[3];
    const int* dst_bwd  = (const int*)d_in[4];
    const float* wrel   = (const float*)d_in[5];
    const float* wloop  = (const float*)d_in[6];
    const float* hbias  = (const float*)d_in[7];
    float* out          = (float*)d_out;

    int N = in_sizes[0] / DFEAT;
    int E = in_sizes[1];
    int M = 2 * N;
    int TE = 2 * E;
    int NB = (M + 127) / 128;        // 1563
    int NB8 = NB * 8;

    unsigned* binned     = (unsigned*)d_ws;                        // [2E]
    unsigned short* xb   = (unsigned short*)(binned + (size_t)TE); // [N*128]
    unsigned short* aggb = xb + (size_t)N * DFEAT;                 // [2N*128]
    int* ghist           = (int*)(aggb + (size_t)M * DFEAT);       // [NB8]
    int* S               = ghist + NB8;                            // [NB8+1]
    int* cursor          = S + NB8 + 1;                            // [NB8]
    // total ~ 12.8 + 25.6 + 51.2 + 0.15 MB ~= 90 MB

    int n4 = N * (DFEAT / 4);
    convert_kernel<<<(n4 + 255) / 256, 256, 0, stream>>>(
        (const float4*)x, (ushort4*)xb, n4);

    hipMemsetAsync(ghist, 0, (size_t)NB8 * 4, stream);

    int binb = ((TE + CH - 1) / CH + 7) & ~7;
    hist_kernel<<<binb, 256, 0, stream>>>(dst_fwd, dst_bwd, ghist, N, E, NB);

    scan_kernel<<<1, 256, 0, stream>>>(ghist, S, cursor, NB8, TE);

    bin_kernel<<<binb, 256, 0, stream>>>(
        src_fwd, dst_fwd, src_bwd, dst_bwd, cursor, binned, N, E);

    agg_kernel<<<NB, 256, 0, stream>>>((const uint2*)xb, binned, S, aggb, M);

    fused_gemm_kernel<<<(N + 31) / 32, 256, 0, stream>>>(
        aggb, x, wrel, wloop, hbias, out, N);
}

// Round 6
// 520.851 us; speedup vs baseline: 5.5462x; 1.2382x over previous
//
#include <hip/hip_runtime.h>
#include <hip/hip_bf16.h>

// R-GCN layer (fp32 in/out): out = relu(agg0/deg0 @ W0 + agg1/deg1 @ W1 + x @ Wl + b)
// Round 6: GEMM -> bf16 MFMA (16x16x32). A = [aggb | aggb(+N) | xb] all bf16;
// B pre-packed into MFMA fragment order (wb). Agg pipeline unchanged.
//
// ws: wb ushort[12*8*64*8] | binned uint[2E] | xb bf16[N*128] |
//     aggb bf16[2N*128] | ghist int[NB*8] | S int[NB*8+1] | cursor int[NB*8]
// Requires N <= 131072 (src packed into 17 bits).

#define DFEAT 128
#define CH 4096          // edges per hist/bin block
#define NBMAX 1600       // max buckets = ceil(2N/128)
#define CAP 3328         // LDS edge capacity per bucket (mean 2048, sd ~45)

typedef __attribute__((ext_vector_type(8))) short short8v;   // 8 bf16 (4 VGPRs)
typedef __attribute__((ext_vector_type(4))) float float4v;   // 4 fp32 acc

__global__ void convert_kernel(const float4* __restrict__ x4,
                               ushort4* __restrict__ xb4, int n4) {
    int i = blockIdx.x * blockDim.x + threadIdx.x;
    if (i >= n4) return;
    float4 v = x4[i];
    ushort4 o;
    o.x = __hip_bfloat16_raw(__float2bfloat16(v.x)).x;
    o.y = __hip_bfloat16_raw(__float2bfloat16(v.y)).x;
    o.z = __hip_bfloat16_raw(__float2bfloat16(v.z)).x;
    o.w = __hip_bfloat16_raw(__float2bfloat16(v.w)).x;
    xb4[i] = o;
}

// Pack B[k][col] (k<256: wrel, else wloop) into MFMA B-fragment order:
// wb[((kc*8+ct)*64 + lane)*8 + j] = bf16(B[kc*32 + (lane>>4)*8 + j][ct*16 + (lane&15)])
__global__ void pack_b_kernel(const float* __restrict__ wrel,
                              const float* __restrict__ wloop,
                              unsigned short* __restrict__ wb) {
    int t = blockIdx.x * blockDim.x + threadIdx.x;   // 0..6143
    if (t >= 12 * 8 * 64) return;
    int lane = t & 63;
    int kbase = (t >> 9) * 32 + (lane >> 4) * 8;     // kc = t>>9
    int col = (((t >> 6) & 7) << 4) + (lane & 15);   // ct*16 + (lane&15)
    ushort4 o[2];
    unsigned short tmp[8];
#pragma unroll
    for (int j = 0; j < 8; ++j) {
        int k = kbase + j;
        float v = (k < 256) ? wrel[k * DFEAT + col] : wloop[(k - 256) * DFEAT + col];
        tmp[j] = __hip_bfloat16_raw(__float2bfloat16(v)).x;
    }
    o[0] = make_ushort4(tmp[0], tmp[1], tmp[2], tmp[3]);
    o[1] = make_ushort4(tmp[4], tmp[5], tmp[6], tmp[7]);
    *(ushort4*)(wb + t * 8)     = o[0];
    *(ushort4*)(wb + t * 8 + 4) = o[1];
}

// LDS-privatized histogram over buckets b=(r*N+dst)>>7, merged per (b, g=blk%8).
__global__ __launch_bounds__(256) void hist_kernel(
        const int* __restrict__ dst0, const int* __restrict__ dst1,
        int* __restrict__ ghist, int N, int E, int NB) {
    __shared__ int h[NBMAX];
    int tid = threadIdx.x;
    for (int i = tid; i < NBMAX; i += 256) h[i] = 0;
    __syncthreads();
    int k = blockIdx.x, g = k & 7;
    int lo = k * CH, hi = min(2 * E, lo + CH);
    for (int i = lo + tid; i < hi; i += 256) {
        int r = (i >= E) ? 1 : 0;
        int e = i - r * E;
        int t = r ? dst1[e] : dst0[e];
        atomicAdd(&h[(r * N + t) >> 7], 1);
    }
    __syncthreads();
    for (int b = tid; b < NB; b += 256) {
        int c = h[b];
        if (c) atomicAdd(&ghist[b * 8 + g], c);
    }
}

// Exclusive scan of ghist[n] -> S (+cursor copy); S[n] = total sentinel.
__global__ __launch_bounds__(256) void scan_kernel(const int* __restrict__ ghist,
                                                   int* __restrict__ S,
                                                   int* __restrict__ cursor,
                                                   int n, int total) {
    __shared__ int psum[256];
    int t = threadIdx.x;
    int cs = (n + 255) / 256;
    int s = 0;
    for (int j = 0; j < cs; ++j) {
        int idx = t * cs + j;
        if (idx < n) s += ghist[idx];
    }
    psum[t] = s; __syncthreads();
    for (int off = 1; off < 256; off <<= 1) {
        int add = (t >= off) ? psum[t - off] : 0;
        __syncthreads();
        psum[t] += add;
        __syncthreads();
    }
    int run = psum[t] - s;
    for (int j = 0; j < cs; ++j) {
        int idx = t * cs + j;
        if (idx < n) { S[idx] = run; cursor[idx] = run; run += ghist[idx]; }
    }
    if (t == 0) S[n] = total;
}

// Scatter packed edges (pl<<17 | src) into bucket regions, per-(b,g) cursors.
__global__ __launch_bounds__(256) void bin_kernel(
        const int* __restrict__ src0, const int* __restrict__ dst0,
        const int* __restrict__ src1, const int* __restrict__ dst1,
        int* __restrict__ cursor, unsigned* __restrict__ binned, int N, int E) {
    int k = blockIdx.x, g = k & 7;
    int lo = k * CH, hi = min(2 * E, lo + CH);
    for (int i = lo + threadIdx.x; i < hi; i += 256) {
        int r = (i >= E) ? 1 : 0;
        int e = i - r * E;
        int s = r ? src1[e] : src0[e];
        int t = r ? dst1[e] : dst0[e];
        int p = r * N + t;
        int slot = atomicAdd(&cursor[(p >> 7) * 8 + g], 1);
        binned[slot] = ((unsigned)(p & 127) << 17) | (unsigned)s;
    }
}

// One block per bucket (128 p's). Build local CSR in LDS, then one half-wave
// (32 lanes) per p: register-accumulate its in-edges via bf16 row gathers.
__global__ __launch_bounds__(256) void agg_kernel(
        const uint2* __restrict__ xb2,        // x bf16 rows as uint2[N][32]
        const unsigned* __restrict__ binned,
        const int* __restrict__ S,
        unsigned short* __restrict__ aggb, int M) {
    __shared__ unsigned ebuf[CAP];
    __shared__ int cnt[128], cur[128], rs[128], sh[128];
    int tid = threadIdx.x;
    int b = blockIdx.x;
    int estart = S[b * 8], eend = S[b * 8 + 8];
    int total = eend - estart;
    int P0 = b << 7;
    int hw = tid >> 5, lane = tid & 31;

    if (total <= CAP) {
        if (tid < 128) cnt[tid] = 0;
        __syncthreads();
        for (int i = estart + tid; i < eend; i += 256)
            atomicAdd(&cnt[binned[i] >> 17], 1);
        __syncthreads();
        if (tid < 128) sh[tid] = cnt[tid];
        __syncthreads();
        for (int off = 1; off < 128; off <<= 1) {
            int add = (tid < 128 && tid >= off) ? sh[tid - off] : 0;
            __syncthreads();
            if (tid < 128) sh[tid] += add;
            __syncthreads();
        }
        if (tid < 128) { rs[tid] = sh[tid] - cnt[tid]; cur[tid] = sh[tid] - cnt[tid]; }
        __syncthreads();
        for (int i = estart + tid; i < eend; i += 256) {
            unsigned v = binned[i];
            int slot = atomicAdd(&cur[v >> 17], 1);
            ebuf[slot] = v;
        }
        __syncthreads();

        for (int pi = 0; pi < 16; ++pi) {
            int pl = hw * 16 + pi;
            int s0 = rs[pl], c = cnt[pl];
            float a0 = 0.f, a1 = 0.f, a2 = 0.f, a3 = 0.f;
            int e = 0;
            for (; e + 4 <= c; e += 4) {
                int sA = ebuf[s0 + e] & 0x1FFFF;
                int sB = ebuf[s0 + e + 1] & 0x1FFFF;
                int sC = ebuf[s0 + e + 2] & 0x1FFFF;
                int sD = ebuf[s0 + e + 3] & 0x1FFFF;
                uint2 gA = xb2[(long long)sA * 32 + lane];
                uint2 gB = xb2[(long long)sB * 32 + lane];
                uint2 gC = xb2[(long long)sC * 32 + lane];
                uint2 gD = xb2[(long long)sD * 32 + lane];
                a0 += __uint_as_float(gA.x << 16) + __uint_as_float(gB.x << 16)
                    + __uint_as_float(gC.x << 16) + __uint_as_float(gD.x << 16);
                a1 += __uint_as_float(gA.x & 0xffff0000u) + __uint_as_float(gB.x & 0xffff0000u)
                    + __uint_as_float(gC.x & 0xffff0000u) + __uint_as_float(gD.x & 0xffff0000u);
                a2 += __uint_as_float(gA.y << 16) + __uint_as_float(gB.y << 16)
                    + __uint_as_float(gC.y << 16) + __uint_as_float(gD.y << 16);
                a3 += __uint_as_float(gA.y & 0xffff0000u) + __uint_as_float(gB.y & 0xffff0000u)
                    + __uint_as_float(gC.y & 0xffff0000u) + __uint_as_float(gD.y & 0xffff0000u);
            }
            for (; e < c; ++e) {
                int s = ebuf[s0 + e] & 0x1FFFF;
                uint2 g = xb2[(long long)s * 32 + lane];
                a0 += __uint_as_float(g.x << 16);
                a1 += __uint_as_float(g.x & 0xffff0000u);
                a2 += __uint_as_float(g.y << 16);
                a3 += __uint_as_float(g.y & 0xffff0000u);
            }
            int pg = P0 + pl;
            if (pg < M) {
                float inv = 1.0f / (float)max(c, 1);
                ushort4 w;
                w.x = __hip_bfloat16_raw(__float2bfloat16(a0 * inv)).x;
                w.y = __hip_bfloat16_raw(__float2bfloat16(a1 * inv)).x;
                w.z = __hip_bfloat16_raw(__float2bfloat16(a2 * inv)).x;
                w.w = __hip_bfloat16_raw(__float2bfloat16(a3 * inv)).x;
                *(ushort4*)(aggb + (long long)pg * DFEAT + 4 * lane) = w;
            }
        }
    } else {
        for (int pi = 0; pi < 16; ++pi) {
            int pl = hw * 16 + pi;
            float a0 = 0.f, a1 = 0.f, a2 = 0.f, a3 = 0.f;
            int c = 0;
            for (int i = estart; i < eend; ++i) {
                unsigned v = binned[i];
                if ((int)(v >> 17) == pl) {
                    ++c;
                    uint2 g = xb2[(long long)(v & 0x1FFFF) * 32 + lane];
                    a0 += __uint_as_float(g.x << 16);
                    a1 += __uint_as_float(g.x & 0xffff0000u);
                    a2 += __uint_as_float(g.y << 16);
                    a3 += __uint_as_float(g.y & 0xffff0000u);
                }
            }
            int pg = P0 + pl;
            if (pg < M) {
                float inv = 1.0f / (float)max(c, 1);
                ushort4 w;
                w.x = __hip_bfloat16_raw(__float2bfloat16(a0 * inv)).x;
                w.y = __hip_bfloat16_raw(__float2bfloat16(a1 * inv)).x;
                w.z = __hip_bfloat16_raw(__float2bfloat16(a2 * inv)).x;
                w.w = __hip_bfloat16_raw(__float2bfloat16(a3 * inv)).x;
                *(ushort4*)(aggb + (long long)pg * DFEAT + 4 * lane) = w;
            }
        }
    }
}

// MFMA GEMM: out[row,col] = relu(sum_k A[row,k]*B[k,col] + bias[col]),
// A row = [aggb[row] | aggb[N+row] | xb[row]] (bf16), B pre-packed (wb).
// Block: 256 thr = 4 waves; 128 rows x 128 cols. Wave: 32 rows (2 tiles) x 8 col-tiles.
__global__ __launch_bounds__(256) void mfma_gemm_kernel(
        const unsigned short* __restrict__ aggb,
        const unsigned short* __restrict__ xb,
        const unsigned short* __restrict__ wb,
        const float* __restrict__ bias,
        float* __restrict__ out, int N) {
    int tid = threadIdx.x;
    int wv = tid >> 6, lane = tid & 63;
    int R0 = blockIdx.x * 128 + wv * 32;
    int mrow = lane & 15, quad = lane >> 4;

    float4v acc[2][8];
#pragma unroll
    for (int rt = 0; rt < 2; ++rt)
#pragma unroll
        for (int ct = 0; ct < 8; ++ct) acc[rt][ct] = (float4v){0.f, 0.f, 0.f, 0.f};

    int n0 = min(R0 + mrow, N - 1);
    int n1 = min(R0 + 16 + mrow, N - 1);

#pragma unroll
    for (int kc = 0; kc < 12; ++kc) {
        int off = (kc & 3) * 32 + quad * 8;
        const unsigned short* s0;
        const unsigned short* s1;
        if (kc < 4)      { s0 = aggb + (size_t)n0 * DFEAT;       s1 = aggb + (size_t)n1 * DFEAT; }
        else if (kc < 8) { s0 = aggb + (size_t)(N + n0) * DFEAT; s1 = aggb + (size_t)(N + n1) * DFEAT; }
        else             { s0 = xb + (size_t)n0 * DFEAT;         s1 = xb + (size_t)n1 * DFEAT; }
        short8v a0 = *(const short8v*)(s0 + off);
        short8v a1 = *(const short8v*)(s1 + off);
#pragma unroll
        for (int ct = 0; ct < 8; ++ct) {
            short8v bfr = *(const short8v*)(wb + (((kc * 8 + ct) << 6) + lane) * 8);
            acc[0][ct] = __builtin_amdgcn_mfma_f32_16x16x32_bf16(a0, bfr, acc[0][ct], 0, 0, 0);
            acc[1][ct] = __builtin_amdgcn_mfma_f32_16x16x32_bf16(a1, bfr, acc[1][ct], 0, 0, 0);
        }
    }

#pragma unroll
    for (int ct = 0; ct < 8; ++ct) {
        int col = ct * 16 + mrow;
        float bv = bias[col];
#pragma unroll
        for (int rt = 0; rt < 2; ++rt) {
#pragma unroll
            for (int i = 0; i < 4; ++i) {
                int row = R0 + rt * 16 + quad * 4 + i;
                if (row < N)
                    out[(size_t)row * DFEAT + col] = fmaxf(acc[rt][ct][i] + bv, 0.f);
            }
        }
    }
}

extern "C" void kernel_launch(void* const* d_in, const int* in_sizes, int n_in,
                              void* d_out, int out_size, void* d_ws, size_t ws_size,
                              hipStream_t stream) {
    const float* x      = (const float*)d_in[0];
    const int* src_fwd  = (const int*)d_in[1];
    const int* dst_fwd  = (const int*)d_in[2];
    const int* src_bwd  = (const int*)d_in[3];
    const int* dst_bwd  = (const int*)d_in[4];
    const float* wrel   = (const float*)d_in[5];
    const float* wloop  = (const float*)d_in[6];
    const float* hbias  = (const float*)d_in[7];
    float* out          = (float*)d_out;

    int N = in_sizes[0] / DFEAT;
    int E = in_sizes[1];
    int M = 2 * N;
    int TE = 2 * E;
    int NB = (M + 127) / 128;        // 1563
    int NB8 = NB * 8;

    unsigned short* wb   = (unsigned short*)d_ws;                  // [12*8*64*8] = 96KB
    unsigned* binned     = (unsigned*)(wb + 12 * 8 * 64 * 8);      // [2E]
    unsigned short* xb   = (unsigned short*)(binned + (size_t)TE); // [N*128]
    unsigned short* aggb = xb + (size_t)N * DFEAT;                 // [2N*128]
    int* ghist           = (int*)(aggb + (size_t)M * DFEAT);       // [NB8]
    int* S               = ghist + NB8;                            // [NB8+1]
    int* cursor          = S + NB8 + 1;                            // [NB8]
    // total ~ 0.1 + 12.8 + 25.6 + 51.2 + 0.15 MB ~= 90 MB

    int n4 = N * (DFEAT / 4);
    convert_kernel<<<(n4 + 255) / 256, 256, 0, stream>>>(
        (const float4*)x, (ushort4*)xb, n4);

    pack_b_kernel<<<24, 256, 0, stream>>>(wrel, wloop, wb);

    hipMemsetAsync(ghist, 0, (size_t)NB8 * 4, stream);

    int binb = ((TE + CH - 1) / CH + 7) & ~7;
    hist_kernel<<<binb, 256, 0, stream>>>(dst_fwd, dst_bwd, ghist, N, E, NB);

    scan_kernel<<<1, 256, 0, stream>>>(ghist, S, cursor, NB8, TE);

    bin_kernel<<<binb, 256, 0, stream>>>(
        src_fwd, dst_fwd, src_bwd, dst_bwd, cursor, binned, N, E);

    agg_kernel<<<NB, 256, 0, stream>>>((const uint2*)xb, binned, S, aggb, M);

    mfma_gemm_kernel<<<(N + 127) / 128, 256, 0, stream>>>(
        aggb, xb, wb, hbias, out, N);
}

// Round 7
// 400.974 us; speedup vs baseline: 7.2043x; 1.2990x over previous
//
#include <hip/hip_runtime.h>
#include <hip/hip_bf16.h>

// R-GCN layer (fp32 in/out): out = relu(agg0/deg0 @ W0 + agg1/deg1 @ W1 + x @ Wl + b)
// Round 7: bin rewritten as block-staged counting scatter with bulk run
// reservation (one global atomic per (block,bucket) instead of per edge;
// contiguous ~40B runs instead of random 4B writes). g-split removed.
//
// ws: wb ushort[12*8*64*8] | binned uint[2E] | xb bf16[N*128] |
//     aggb bf16[2N*128] | ghist int[NB] | S int[NB+1] | cursor int[NB]
// Requires N <= 131072 (src packed into 17 bits).

#define DFEAT 128
#define CH2 16384        // edges per hist/bin block
#define NBMAX 1600       // max buckets = ceil(2N/128)
#define CAP 3328         // LDS edge capacity per bucket (mean 2048, sd ~45)

typedef __attribute__((ext_vector_type(8))) short short8v;   // 8 bf16 (4 VGPRs)
typedef __attribute__((ext_vector_type(4))) float float4v;   // 4 fp32 acc

__global__ void convert_kernel(const float4* __restrict__ x4,
                               ushort4* __restrict__ xb4, int n4) {
    int i = blockIdx.x * blockDim.x + threadIdx.x;
    if (i >= n4) return;
    float4 v = x4[i];
    ushort4 o;
    o.x = __hip_bfloat16_raw(__float2bfloat16(v.x)).x;
    o.y = __hip_bfloat16_raw(__float2bfloat16(v.y)).x;
    o.z = __hip_bfloat16_raw(__float2bfloat16(v.z)).x;
    o.w = __hip_bfloat16_raw(__float2bfloat16(v.w)).x;
    xb4[i] = o;
}

// Pack B[k][col] (k<256: wrel, else wloop) into MFMA B-fragment order:
// wb[((kc*8+ct)*64 + lane)*8 + j] = bf16(B[kc*32 + (lane>>4)*8 + j][ct*16 + (lane&15)])
__global__ void pack_b_kernel(const float* __restrict__ wrel,
                              const float* __restrict__ wloop,
                              unsigned short* __restrict__ wb) {
    int t = blockIdx.x * blockDim.x + threadIdx.x;   // 0..6143
    if (t >= 12 * 8 * 64) return;
    int lane = t & 63;
    int kbase = (t >> 9) * 32 + (lane >> 4) * 8;
    int col = (((t >> 6) & 7) << 4) + (lane & 15);
    unsigned short tmp[8];
#pragma unroll
    for (int j = 0; j < 8; ++j) {
        int k = kbase + j;
        float v = (k < 256) ? wrel[k * DFEAT + col] : wloop[(k - 256) * DFEAT + col];
        tmp[j] = __hip_bfloat16_raw(__float2bfloat16(v)).x;
    }
    *(ushort4*)(wb + t * 8)     = make_ushort4(tmp[0], tmp[1], tmp[2], tmp[3]);
    *(ushort4*)(wb + t * 8 + 4) = make_ushort4(tmp[4], tmp[5], tmp[6], tmp[7]);
}

__global__ void zero_kernel(int* __restrict__ p, int n) {
    int i = blockIdx.x * blockDim.x + threadIdx.x;
    if (i < n) p[i] = 0;
}

// Global bucket histogram, LDS-privatized; one merge atomic per (block,bucket).
__global__ __launch_bounds__(256) void hist_kernel(
        const int* __restrict__ dst0, const int* __restrict__ dst1,
        int* __restrict__ ghist, int N, int E, int NB) {
    __shared__ int h[NBMAX];
    int tid = threadIdx.x;
    for (int i = tid; i < NBMAX; i += 256) h[i] = 0;
    __syncthreads();
    int lo = blockIdx.x * CH2, hi = min(2 * E, lo + CH2);
    for (int i = lo + tid; i < hi; i += 256) {
        int r = (i >= E) ? 1 : 0;
        int e = i - r * E;
        int t = r ? dst1[e] : dst0[e];
        atomicAdd(&h[(r * N + t) >> 7], 1);
    }
    __syncthreads();
    for (int b = tid; b < NB; b += 256) {
        int c = h[b];
        if (c) atomicAdd(&ghist[b], c);
    }
}

// Exclusive scan of ghist[n] -> S (+cursor copy); S[n] = total sentinel.
__global__ __launch_bounds__(256) void scan_kernel(const int* __restrict__ ghist,
                                                   int* __restrict__ S,
                                                   int* __restrict__ cursor,
                                                   int n, int total) {
    __shared__ int psum[256];
    int t = threadIdx.x;
    int cs = (n + 255) / 256;
    int s = 0;
    for (int j = 0; j < cs; ++j) {
        int idx = t * cs + j;
        if (idx < n) s += ghist[idx];
    }
    psum[t] = s; __syncthreads();
    for (int off = 1; off < 256; off <<= 1) {
        int add = (t >= off) ? psum[t - off] : 0;
        __syncthreads();
        psum[t] += add;
        __syncthreads();
    }
    int run = psum[t] - s;
    for (int j = 0; j < cs; ++j) {
        int idx = t * cs + j;
        if (idx < n) { S[idx] = run; cursor[idx] = run; run += ghist[idx]; }
    }
    if (t == 0) S[n] = total;
}

// Block-staged scatter: pass 1 local hist; bulk-reserve one run per
// (block,bucket); pass 2 re-read edges (L2-hot) and write into the run via
// LDS bump. Writes are contiguous ~10-edge runs -> low line amplification.
__global__ __launch_bounds__(256) void bin_kernel(
        const int* __restrict__ src0, const int* __restrict__ dst0,
        const int* __restrict__ src1, const int* __restrict__ dst1,
        int* __restrict__ cursor, unsigned* __restrict__ binned, int N, int E) {
    __shared__ int cnt[NBMAX];
    __shared__ int base[NBMAX];
    int tid = threadIdx.x;
    for (int i = tid; i < NBMAX; i += 256) cnt[i] = 0;
    __syncthreads();
    int lo = blockIdx.x * CH2, hi = min(2 * E, lo + CH2);
    // pass 1: local histogram
    for (int i = lo + tid; i < hi; i += 256) {
        int r = (i >= E) ? 1 : 0;
        int e = i - r * E;
        int t = r ? dst1[e] : dst0[e];
        atomicAdd(&cnt[(r * N + t) >> 7], 1);
    }
    __syncthreads();
    // reserve contiguous runs
    for (int b = tid; b < NBMAX; b += 256) {
        int c = cnt[b];
        if (c) base[b] = atomicAdd(&cursor[b], c);
    }
    __syncthreads();
    // pass 2: scatter into runs
    for (int i = lo + tid; i < hi; i += 256) {
        int r = (i >= E) ? 1 : 0;
        int e = i - r * E;
        int s = r ? src1[e] : src0[e];
        int t = r ? dst1[e] : dst0[e];
        int p = r * N + t;
        int slot = atomicAdd(&base[p >> 7], 1);
        binned[slot] = ((unsigned)(p & 127) << 17) | (unsigned)s;
    }
}

// One block per bucket (128 p's). Build local CSR in LDS, then one half-wave
// (32 lanes) per p: register-accumulate its in-edges via bf16 row gathers.
__global__ __launch_bounds__(256) void agg_kernel(
        const uint2* __restrict__ xb2,        // x bf16 rows as uint2[N][32]
        const unsigned* __restrict__ binned,
        const int* __restrict__ S,
        unsigned short* __restrict__ aggb, int M) {
    __shared__ unsigned ebuf[CAP];
    __shared__ int cnt[128], cur[128], rs[128], sh[128];
    int tid = threadIdx.x;
    int b = blockIdx.x;
    int estart = S[b], eend = S[b + 1];
    int total = eend - estart;
    int P0 = b << 7;
    int hw = tid >> 5, lane = tid & 31;

    if (total <= CAP) {
        if (tid < 128) cnt[tid] = 0;
        __syncthreads();
        for (int i = estart + tid; i < eend; i += 256)
            atomicAdd(&cnt[binned[i] >> 17], 1);
        __syncthreads();
        if (tid < 128) sh[tid] = cnt[tid];
        __syncthreads();
        for (int off = 1; off < 128; off <<= 1) {
            int add = (tid < 128 && tid >= off) ? sh[tid - off] : 0;
            __syncthreads();
            if (tid < 128) sh[tid] += add;
            __syncthreads();
        }
        if (tid < 128) { rs[tid] = sh[tid] - cnt[tid]; cur[tid] = sh[tid] - cnt[tid]; }
        __syncthreads();
        for (int i = estart + tid; i < eend; i += 256) {
            unsigned v = binned[i];
            int slot = atomicAdd(&cur[v >> 17], 1);
            ebuf[slot] = v;
        }
        __syncthreads();

        for (int pi = 0; pi < 16; ++pi) {
            int pl = hw * 16 + pi;
            int s0 = rs[pl], c = cnt[pl];
            float a0 = 0.f, a1 = 0.f, a2 = 0.f, a3 = 0.f;
            int e = 0;
            for (; e + 4 <= c; e += 4) {
                int sA = ebuf[s0 + e] & 0x1FFFF;
                int sB = ebuf[s0 + e + 1] & 0x1FFFF;
                int sC = ebuf[s0 + e + 2] & 0x1FFFF;
                int sD = ebuf[s0 + e + 3] & 0x1FFFF;
                uint2 gA = xb2[(long long)sA * 32 + lane];
                uint2 gB = xb2[(long long)sB * 32 + lane];
                uint2 gC = xb2[(long long)sC * 32 + lane];
                uint2 gD = xb2[(long long)sD * 32 + lane];
                a0 += __uint_as_float(gA.x << 16) + __uint_as_float(gB.x << 16)
                    + __uint_as_float(gC.x << 16) + __uint_as_float(gD.x << 16);
                a1 += __uint_as_float(gA.x & 0xffff0000u) + __uint_as_float(gB.x & 0xffff0000u)
                    + __uint_as_float(gC.x & 0xffff0000u) + __uint_as_float(gD.x & 0xffff0000u);
                a2 += __uint_as_float(gA.y << 16) + __uint_as_float(gB.y << 16)
                    + __uint_as_float(gC.y << 16) + __uint_as_float(gD.y << 16);
                a3 += __uint_as_float(gA.y & 0xffff0000u) + __uint_as_float(gB.y & 0xffff0000u)
                    + __uint_as_float(gC.y & 0xffff0000u) + __uint_as_float(gD.y & 0xffff0000u);
            }
            for (; e < c; ++e) {
                int s = ebuf[s0 + e] & 0x1FFFF;
                uint2 g = xb2[(long long)s * 32 + lane];
                a0 += __uint_as_float(g.x << 16);
                a1 += __uint_as_float(g.x & 0xffff0000u);
                a2 += __uint_as_float(g.y << 16);
                a3 += __uint_as_float(g.y & 0xffff0000u);
            }
            int pg = P0 + pl;
            if (pg < M) {
                float inv = 1.0f / (float)max(c, 1);
                ushort4 w;
                w.x = __hip_bfloat16_raw(__float2bfloat16(a0 * inv)).x;
                w.y = __hip_bfloat16_raw(__float2bfloat16(a1 * inv)).x;
                w.z = __hip_bfloat16_raw(__float2bfloat16(a2 * inv)).x;
                w.w = __hip_bfloat16_raw(__float2bfloat16(a3 * inv)).x;
                *(ushort4*)(aggb + (long long)pg * DFEAT + 4 * lane) = w;
            }
        }
    } else {
        for (int pi = 0; pi < 16; ++pi) {
            int pl = hw * 16 + pi;
            float a0 = 0.f, a1 = 0.f, a2 = 0.f, a3 = 0.f;
            int c = 0;
            for (int i = estart; i < eend; ++i) {
                unsigned v = binned[i];
                if ((int)(v >> 17) == pl) {
                    ++c;
                    uint2 g = xb2[(long long)(v & 0x1FFFF) * 32 + lane];
                    a0 += __uint_as_float(g.x << 16);
                    a1 += __uint_as_float(g.x & 0xffff0000u);
                    a2 += __uint_as_float(g.y << 16);
                    a3 += __uint_as_float(g.y & 0xffff0000u);
                }
            }
            int pg = P0 + pl;
            if (pg < M) {
                float inv = 1.0f / (float)max(c, 1);
                ushort4 w;
                w.x = __hip_bfloat16_raw(__float2bfloat16(a0 * inv)).x;
                w.y = __hip_bfloat16_raw(__float2bfloat16(a1 * inv)).x;
                w.z = __hip_bfloat16_raw(__float2bfloat16(a2 * inv)).x;
                w.w = __hip_bfloat16_raw(__float2bfloat16(a3 * inv)).x;
                *(ushort4*)(aggb + (long long)pg * DFEAT + 4 * lane) = w;
            }
        }
    }
}

// MFMA GEMM: out[row,col] = relu(sum_k A[row,k]*B[k,col] + bias[col]),
// A row = [aggb[row] | aggb[N+row] | xb[row]] (bf16), B pre-packed (wb).
__global__ __launch_bounds__(256) void mfma_gemm_kernel(
        const unsigned short* __restrict__ aggb,
        const unsigned short* __restrict__ xb,
        const unsigned short* __restrict__ wb,
        const float* __restrict__ bias,
        float* __restrict__ out, int N) {
    int tid = threadIdx.x;
    int wv = tid >> 6, lane = tid & 63;
    int R0 = blockIdx.x * 128 + wv * 32;
    int mrow = lane & 15, quad = lane >> 4;

    float4v acc[2][8];
#pragma unroll
    for (int rt = 0; rt < 2; ++rt)
#pragma unroll
        for (int ct = 0; ct < 8; ++ct) acc[rt][ct] = (float4v){0.f, 0.f, 0.f, 0.f};

    int n0 = min(R0 + mrow, N - 1);
    int n1 = min(R0 + 16 + mrow, N - 1);

#pragma unroll
    for (int kc = 0; kc < 12; ++kc) {
        int off = (kc & 3) * 32 + quad * 8;
        const unsigned short* s0;
        const unsigned short* s1;
        if (kc < 4)      { s0 = aggb + (size_t)n0 * DFEAT;       s1 = aggb + (size_t)n1 * DFEAT; }
        else if (kc < 8) { s0 = aggb + (size_t)(N + n0) * DFEAT; s1 = aggb + (size_t)(N + n1) * DFEAT; }
        else             { s0 = xb + (size_t)n0 * DFEAT;         s1 = xb + (size_t)n1 * DFEAT; }
        short8v a0 = *(const short8v*)(s0 + off);
        short8v a1 = *(const short8v*)(s1 + off);
#pragma unroll
        for (int ct = 0; ct < 8; ++ct) {
            short8v bfr = *(const short8v*)(wb + (((kc * 8 + ct) << 6) + lane) * 8);
            acc[0][ct] = __builtin_amdgcn_mfma_f32_16x16x32_bf16(a0, bfr, acc[0][ct], 0, 0, 0);
            acc[1][ct] = __builtin_amdgcn_mfma_f32_16x16x32_bf16(a1, bfr, acc[1][ct], 0, 0, 0);
        }
    }

#pragma unroll
    for (int ct = 0; ct < 8; ++ct) {
        int col = ct * 16 + mrow;
        float bv = bias[col];
#pragma unroll
        for (int rt = 0; rt < 2; ++rt) {
#pragma unroll
            for (int i = 0; i < 4; ++i) {
                int row = R0 + rt * 16 + quad * 4 + i;
                if (row < N)
                    out[(size_t)row * DFEAT + col] = fmaxf(acc[rt][ct][i] + bv, 0.f);
            }
        }
    }
}

extern "C" void kernel_launch(void* const* d_in, const int* in_sizes, int n_in,
                              void* d_out, int out_size, void* d_ws, size_t ws_size,
                              hipStream_t stream) {
    const float* x      = (const float*)d_in[0];
    const int* src_fwd  = (const int*)d_in[1];
    const int* dst_fwd  = (const int*)d_in[2];
    const int* src_bwd  = (const int*)d_in[3];
    const int* dst_bwd  = (const int*)d_in[4];
    const float* wrel   = (const float*)d_in[5];
    const float* wloop  = (const float*)d_in[6];
    const float* hbias  = (const float*)d_in[7];
    float* out          = (float*)d_out;

    int N = in_sizes[0] / DFEAT;
    int E = in_sizes[1];
    int M = 2 * N;
    int TE = 2 * E;
    int NB = (M + 127) / 128;        // 1563

    unsigned short* wb   = (unsigned short*)d_ws;                  // 96KB
    unsigned* binned     = (unsigned*)(wb + 12 * 8 * 64 * 8);      // [2E]
    unsigned short* xb   = (unsigned short*)(binned + (size_t)TE); // [N*128]
    unsigned short* aggb = xb + (size_t)N * DFEAT;                 // [2N*128]
    int* ghist           = (int*)(aggb + (size_t)M * DFEAT);       // [NB]
    int* S               = ghist + NB;                             // [NB+1]
    int* cursor          = S + NB + 1;                             // [NB]

    int n4 = N * (DFEAT / 4);
    convert_kernel<<<(n4 + 255) / 256, 256, 0, stream>>>(
        (const float4*)x, (ushort4*)xb, n4);

    pack_b_kernel<<<24, 256, 0, stream>>>(wrel, wloop, wb);

    zero_kernel<<<(NB + 255) / 256, 256, 0, stream>>>(ghist, NB);

    int nblk = (TE + CH2 - 1) / CH2;   // 196
    hist_kernel<<<nblk, 256, 0, stream>>>(dst_fwd, dst_bwd, ghist, N, E, NB);

    scan_kernel<<<1, 256, 0, stream>>>(ghist, S, cursor, NB, TE);

    bin_kernel<<<nblk, 256, 0, stream>>>(
        src_fwd, dst_fwd, src_bwd, dst_bwd, cursor, binned, N, E);

    agg_kernel<<<NB, 256, 0, stream>>>((const uint2*)xb, binned, S, aggb, M);

    mfma_gemm_kernel<<<(N + 127) / 128, 256, 0, stream>>>(
        aggb, xb, wb, hbias, out, N);
}